// Round 11
// baseline (399.485 us; speedup 1.0000x reference)
//
#include <hip/hip_runtime.h>
#include <hip/hip_bf16.h>
#include <stdint.h>

// Problem: out[m,n] = sum_k fp8(inp[m,k]) * fp8(weight[n,k]) + bias[n]
// M=8192, K=4096, N=4096. inp/weight fp32 -> e4m3fn (RNE), fp32 accumulate.
//
// Round 11 (resubmit #3 of the m201-style structure; broker timeouts).
// 256x256 tile, 512 threads / 8 waves (2Mx4N), wave = 128x64 = 4x2 frags of
// 32x32x64 MX-scaled MFMA (unit scales). 2 LDS buffers (64 KiB), depth-2
// counted-vmcnt pipeline (vmcnt(4)), two raw barriers/iter, setprio around
// MFMA clusters (T5).

#define MD 8192
#define KD 4096
#define ND 4096
#define BM 256
#define BN 256
#define BK 64

using f32x16 = __attribute__((ext_vector_type(16))) float;
using i32x4  = __attribute__((ext_vector_type(4))) int;
using i32x8  = __attribute__((ext_vector_type(8))) int;

// -------------------------------------------------------------------------
// Fused quantize fp32 -> fp8 e4m3 (validated r7/r8; unchanged)
// -------------------------------------------------------------------------
__device__ __forceinline__ int q4(float4 f) {
  int v = 0;
  v = __builtin_amdgcn_cvt_pk_fp8_f32(f.x, f.y, v, false);
  v = __builtin_amdgcn_cvt_pk_fp8_f32(f.z, f.w, v, true);
  return v;
}

__global__ __launch_bounds__(256) void quant_fp8_fused_kernel(
    const float* __restrict__ inA, const float* __restrict__ inW,
    uint8_t* __restrict__ outA, uint8_t* __restrict__ outW) {
  const int NA16 = MD * KD / 16;
  const int NW16 = ND * KD / 16;
  const int tid = blockIdx.x * blockDim.x + threadIdx.x;
  const int stride = gridDim.x * blockDim.x;

  for (int i = tid; i < NA16; i += stride) {
    const float4* p = (const float4*)inA + (size_t)i * 4;
    int4 v = make_int4(q4(p[0]), q4(p[1]), q4(p[2]), q4(p[3]));
    ((int4*)outA)[i] = v;
  }
  for (int i = tid; i < NW16; i += stride) {
    const float4* p = (const float4*)inW + (size_t)i * 4;
    int4 v = make_int4(q4(p[0]), q4(p[1]), q4(p[2]), q4(p[3]));
    ((int4*)outW)[i] = v;
  }
}

// -------------------------------------------------------------------------
// MX-FP8 GEMM (A: MxK, B: NxK, C = A*B^T + bias), unit block scales.
// Block 256x256, BK=64, 8 waves (2x4), wave = 128x64 = 4x2 frags of 32x32.
// Staging: global_load_lds width=16, linear LDS dest (thread t -> t*16),
// pre-swizzled source: LDS chunk q of row r holds global chunk q^((r>>1)&3).
// -------------------------------------------------------------------------
__device__ __forceinline__ void gload16(const uint8_t* g, uint8_t* l) {
  __builtin_amdgcn_global_load_lds(
      (const __attribute__((address_space(1))) void*)g,
      (__attribute__((address_space(3))) void*)l, 16, 0, 0);
}

__global__ __launch_bounds__(512, 2) void fp8mx_gemm_bias_kernel(
    const uint8_t* __restrict__ A, const uint8_t* __restrict__ B,
    const __hip_bfloat16* __restrict__ bias, float* __restrict__ C) {
  // per buffer: A 256x64 = 16 KiB @0, B 256x64 = 16 KiB @16384; 2 bufs = 64 KiB
  __shared__ uint8_t sm[2][32768];

  // ---- rasterization: 512 blocks (32 tm x 16 tn), XCD-chunked (512%8==0) ----
  const int bid = blockIdx.x;
  const int xcd = bid & 7;
  const int li = bid >> 3;               // 0..63 within XCD chunk
  const int tm = xcd * 4 + (li >> 4);    // 0..31
  const int tn = li & 15;                // 0..15

  const int t = threadIdx.x;             // 0..511
  const int w = t >> 6;                  // wave 0..7
  const int l = t & 63;
  const int wm = w >> 2, wn = w & 3;     // 2 x 4 wave grid
  const int r31 = l & 31, kh = l >> 5;

  // ---- staging (thread t: row = t>>2 in 0..127, chunk = t&3) ----
  const int row_s = t >> 2;
  const int gsw = (t & 3) ^ ((row_s >> 1) & 3);   // pre-swizzled source chunk
  const size_t abase = (size_t)(tm * BM + row_s) * KD + gsw * 16;
  const size_t bbase = (size_t)(tn * BN + row_s) * KD + gsw * 16;
  const int wd = w * 1024;               // wave-uniform LDS base (HW adds l*16)

  // ---- fragment read chunk offsets: lane needs k-chunks {2kh, 2kh+1} ----
  const int s = (r31 >> 1) & 3;
  const int cLo = (((kh << 1) | 0) ^ s) * 16;
  const int cHi = (((kh << 1) | 1) ^ s) * 16;

  f32x16 acc[4][2];
#pragma unroll
  for (int fm = 0; fm < 4; ++fm)
#pragma unroll
    for (int fn = 0; fn < 2; ++fn)
#pragma unroll
      for (int r = 0; r < 16; ++r) acc[fm][fn][r] = 0.f;

  auto stage = [&](int buf, int kt) {
    const size_t ko = (size_t)kt * BK;
    gload16(A + abase + ko, &sm[buf][wd]);                           // A rows 0..127
    gload16(A + abase + (size_t)128 * KD + ko, &sm[buf][8192 + wd]); // A rows 128..255
    gload16(B + bbase + ko, &sm[buf][16384 + wd]);                   // B rows 0..127
    gload16(B + bbase + (size_t)128 * KD + ko, &sm[buf][24576 + wd]);// B rows 128..255
  };

  auto ldA = [&](const uint8_t* sa, int fm) -> i32x8 {
    const int ra = (wm * 128 + fm * 32 + r31) * 64;
    i32x4 lo = *(const i32x4*)(sa + ra + cLo);
    i32x4 hi = *(const i32x4*)(sa + ra + cHi);
    i32x8 f;
#pragma unroll
    for (int j = 0; j < 4; ++j) { f[j] = lo[j]; f[4 + j] = hi[j]; }
    return f;
  };
  auto ldB = [&](const uint8_t* sb, int fn) -> i32x8 {
    const int rb = (wn * 64 + fn * 32 + r31) * 64;
    i32x4 lo = *(const i32x4*)(sb + rb + cLo);
    i32x4 hi = *(const i32x4*)(sb + rb + cHi);
    i32x8 f;
#pragma unroll
    for (int j = 0; j < 4; ++j) { f[j] = lo[j]; f[4 + j] = hi[j]; }
    return f;
  };

  auto compute = [&](int buf) {
    const uint8_t* sa = &sm[buf][0];
    const uint8_t* sb = &sm[buf][16384];
    // phase A: B frags + A half 0, then 4 MFMA
    i32x8 bf0 = ldB(sb, 0), bf1 = ldB(sb, 1);
    i32x8 af0 = ldA(sa, 0), af1 = ldA(sa, 1);
    __builtin_amdgcn_s_setprio(1);
    acc[0][0] = __builtin_amdgcn_mfma_scale_f32_32x32x64_f8f6f4(
        af0, bf0, acc[0][0], 0, 0, 0, 0x7F7F7F7F, 0, 0x7F7F7F7F);
    acc[0][1] = __builtin_amdgcn_mfma_scale_f32_32x32x64_f8f6f4(
        af0, bf1, acc[0][1], 0, 0, 0, 0x7F7F7F7F, 0, 0x7F7F7F7F);
    acc[1][0] = __builtin_amdgcn_mfma_scale_f32_32x32x64_f8f6f4(
        af1, bf0, acc[1][0], 0, 0, 0, 0x7F7F7F7F, 0, 0x7F7F7F7F);
    acc[1][1] = __builtin_amdgcn_mfma_scale_f32_32x32x64_f8f6f4(
        af1, bf1, acc[1][1], 0, 0, 0, 0x7F7F7F7F, 0, 0x7F7F7F7F);
    __builtin_amdgcn_s_setprio(0);
    // phase B: A half 1, then 4 MFMA
    i32x8 af2 = ldA(sa, 2), af3 = ldA(sa, 3);
    __builtin_amdgcn_s_setprio(1);
    acc[2][0] = __builtin_amdgcn_mfma_scale_f32_32x32x64_f8f6f4(
        af2, bf0, acc[2][0], 0, 0, 0, 0x7F7F7F7F, 0, 0x7F7F7F7F);
    acc[2][1] = __builtin_amdgcn_mfma_scale_f32_32x32x64_f8f6f4(
        af2, bf1, acc[2][1], 0, 0, 0, 0x7F7F7F7F, 0, 0x7F7F7F7F);
    acc[3][0] = __builtin_amdgcn_mfma_scale_f32_32x32x64_f8f6f4(
        af3, bf0, acc[3][0], 0, 0, 0, 0x7F7F7F7F, 0, 0x7F7F7F7F);
    acc[3][1] = __builtin_amdgcn_mfma_scale_f32_32x32x64_f8f6f4(
        af3, bf1, acc[3][1], 0, 0, 0, 0x7F7F7F7F, 0, 0x7F7F7F7F);
    __builtin_amdgcn_s_setprio(0);
  };

  // ---- depth-2 counted-vmcnt pipeline, 2 buffers ----
  // top of iter kt: buf kt&1 ready; tile kt+1's 4 loads in flight.
  const int NT = KD / BK;  // 64
  stage(0, 0);
  stage(1, 1);
  asm volatile("s_waitcnt vmcnt(4)" ::: "memory");  // retire tile 0
  __builtin_amdgcn_s_barrier();
#pragma unroll 1
  for (int kt = 0; kt < NT; ++kt) {
    const int c = kt & 1;
    compute(c);
    if (kt == NT - 1) break;
    __builtin_amdgcn_s_barrier();          // all waves done reading buf c
    if (kt + 2 < NT) {
      stage(c, kt + 2);                    // overwrite buf c (freed above)
      asm volatile("s_waitcnt vmcnt(4)" ::: "memory");  // retire tile kt+1
    } else {
      asm volatile("s_waitcnt vmcnt(0)" ::: "memory");  // retire last tile
    }
    __builtin_amdgcn_s_barrier();          // buf c^1 fully staged
  }

  // ---- epilogue: 32x32 C/D layout:
  //      col = lane&31, row = (reg&3) + 8*(reg>>2) + 4*(lane>>5) ----
#pragma unroll
  for (int fn = 0; fn < 2; ++fn) {
    const int col = tn * BN + wn * 64 + fn * 32 + r31;
    const float bv = __bfloat162float(bias[col]);
#pragma unroll
    for (int fm = 0; fm < 4; ++fm) {
      const int row0 = tm * BM + wm * 128 + fm * 32 + 4 * kh;
      const f32x16 v = acc[fm][fn];
#pragma unroll
      for (int r = 0; r < 16; ++r) {
        const int row = row0 + (r & 3) + 8 * (r >> 2);
        C[(size_t)row * ND + col] = v[r] + bv;
      }
    }
  }
}

// -------------------------------------------------------------------------
extern "C" void kernel_launch(void* const* d_in, const int* in_sizes, int n_in,
                              void* d_out, int out_size, void* d_ws, size_t ws_size,
                              hipStream_t stream) {
  const float* inp = (const float*)d_in[0];            // (M,K) fp32
  const float* wgt = (const float*)d_in[1];            // (N,K) fp32
  const __hip_bfloat16* bias = (const __hip_bfloat16*)d_in[2];  // (N,) bf16
  float* out = (float*)d_out;                           // (M,N) fp32

  uint8_t* a8 = (uint8_t*)d_ws;                         // M*K fp8 = 32 MiB
  uint8_t* b8 = a8 + (size_t)MD * KD;                   // N*K fp8 = 16 MiB

  quant_fp8_fused_kernel<<<2048, 256, 0, stream>>>(inp, wgt, a8, b8);
  fp8mx_gemm_bias_kernel<<<512, 512, 0, stream>>>(a8, b8, bias, out);
}